// Round 8
// baseline (256.449 us; speedup 1.0000x reference)
//
#include <hip/hip_runtime.h>
#include <hip/hip_bf16.h>

#define BB 8
#define NN 2048
#define EE 64
#define DD 256

typedef __attribute__((ext_vector_type(8))) short short8;
typedef __attribute__((ext_vector_type(4))) float f32x4;
typedef __attribute__((ext_vector_type(4))) unsigned short ushort4v;

#define MFMA16(a, b, c) __builtin_amdgcn_mfma_f32_16x16x32_bf16((a), (b), (c), 0, 0, 0)

#if __has_builtin(__builtin_amdgcn_exp2f)
#define EXP2(x) __builtin_amdgcn_exp2f(x)
#else
#define EXP2(x) exp2f(x)
#endif

__device__ inline void gload16(const void* g, void* l) {
  __builtin_amdgcn_global_load_lds(
      (const __attribute__((address_space(1))) unsigned int*)g,
      (__attribute__((address_space(3))) unsigned int*)l, 16, 0, 0);
}

__device__ inline float bf2f(unsigned short u) {
  union { unsigned int i; float f; } v;
  v.i = ((unsigned int)u) << 16;
  return v.f;
}
__device__ inline unsigned short f2bf(float f) {
  union { float f; unsigned int i; } v;
  v.f = f;
  unsigned int r = v.i + 0x7FFFu + ((v.i >> 16) & 1u);
  return (unsigned short)(r >> 16);
}

// ---------------------------------------------------------------------------
// Kernel P: combine weights, convert to bf16.
// ---------------------------------------------------------------------------
__global__ __launch_bounds__(128) void kprep(
    const float* __restrict__ wq_w, const float* __restrict__ wq_b,
    const float* __restrict__ wk_w, const float* __restrict__ wk_b,
    const float* __restrict__ wv_w, const float* __restrict__ mq_w,
    const float* __restrict__ mq_b, const float* __restrict__ mk_w,
    const float* __restrict__ mk_b, const float* __restrict__ out_w,
    const float* __restrict__ ffn_w,
    unsigned short* __restrict__ wqc, float* __restrict__ bqc,
    unsigned short* __restrict__ wkc, float* __restrict__ bkc,
    unsigned short* __restrict__ wvc, unsigned short* __restrict__ outwb,
    unsigned short* __restrict__ ffnwb) {
  const float SC = 0.18033688011112042f;  // log2(e)/8
  int o = blockIdx.x;
  int t = threadIdx.x;
  if (t < 64) {
    float acc = 0.f;
#pragma unroll 4
    for (int d = 0; d < 256; d++) acc += mq_w[o * 256 + d] * wq_w[d * 64 + t];
    wqc[o * 64 + t] = f2bf(acc * SC);
  } else {
    int k = t - 64;
    float acc = 0.f;
#pragma unroll 4
    for (int d = 0; d < 256; d++) acc += mk_w[o * 256 + d] * wk_w[d * 64 + k];
    wkc[o * 64 + k] = f2bf(acc);
  }
  if (t == 0) {
    float acc = 0.f;
    for (int d = 0; d < 256; d++) acc += mq_w[o * 256 + d] * wq_b[d];
    bqc[o] = (acc + mq_b[o]) * SC;
  }
  if (t == 64) {
    float acc = 0.f;
    for (int d = 0; d < 256; d++) acc += mk_w[o * 256 + d] * wk_b[d];
    bkc[o] = acc + mk_b[o];
  }
  int gid = o * 128 + t;
  if (gid < 16384) {
    wvc[gid] = f2bf(wv_w[gid]);
    outwb[gid] = f2bf(out_w[gid]);
  }
  if (gid < 4096) ffnwb[gid] = f2bf(ffn_w[gid]);
}

// ---------------------------------------------------------------------------
// Kernel 1: LayerNorm + q/k/v projections (v stored transposed).
// ---------------------------------------------------------------------------
__global__ __launch_bounds__(128, 2) void kproj(
    const float* __restrict__ x, const float* __restrict__ ln_g,
    const float* __restrict__ ln_b, const unsigned short* __restrict__ wqc,
    const float* __restrict__ bqc, const unsigned short* __restrict__ wkc,
    const float* __restrict__ bkc, const unsigned short* __restrict__ wvc,
    const float* __restrict__ wv_b, unsigned short* __restrict__ qout,
    unsigned short* __restrict__ kout, unsigned short* __restrict__ vtout) {
  __shared__ __align__(1024) char lds[2 * 10240];
  int tid = threadIdx.x;
  int w = tid >> 6, l = tid & 63;
  int c = l & 15, g = l >> 4;
  int blk = blockIdx.x;
  int b = blk >> 6;
  int i0 = (blk & 63) * 32 + w * 16;
  size_t row0 = (size_t)b * NN + i0;
  char* xnb = lds + w * 10240;
  char* tlb = lds + w * 10240 + 2048;

  int rl = l >> 2;
  int cc = (l & 3) * 16;
  float xv[16];
  {
    const float* xr = x + (row0 + rl) * EE + cc;
#pragma unroll
    for (int i = 0; i < 4; i++) {
      float4 v = *(const float4*)(xr + i * 4);
      xv[i * 4 + 0] = v.x; xv[i * 4 + 1] = v.y;
      xv[i * 4 + 2] = v.z; xv[i * 4 + 3] = v.w;
    }
  }
  float s = 0.f, s2 = 0.f;
#pragma unroll
  for (int i = 0; i < 16; i++) { s += xv[i]; s2 += xv[i] * xv[i]; }
  s += __shfl_xor(s, 1); s += __shfl_xor(s, 2);
  s2 += __shfl_xor(s2, 1); s2 += __shfl_xor(s2, 2);
  float mean = s * (1.f / 64.f);
  float var = s2 * (1.f / 64.f) - mean * mean;
  float rstd = rsqrtf(var + 1e-5f);
  {
    int swzr = (rl & 7) << 4;
    unsigned short pk[16];
#pragma unroll
    for (int i = 0; i < 16; i++)
      pk[i] = f2bf((xv[i] - mean) * rstd * ln_g[cc + i] + ln_b[cc + i]);
#pragma unroll
    for (int hh = 0; hh < 2; hh++) {
      short8 d;
#pragma unroll
      for (int i = 0; i < 8; i++) d[i] = (short)pk[hh * 8 + i];
      *(short8*)(xnb + rl * 128 + (((l & 3) * 32 + hh * 16) ^ swzr)) = d;
    }
  }
  __syncthreads();

  int swz = (c & 7) << 4;
  int o2_0 = (g * 16) ^ swz;
  int o2_1 = (64 + g * 16) ^ swz;
  short8 af0 = *(const short8*)(xnb + c * 128 + o2_0);
  short8 af1 = *(const short8*)(xnb + c * 128 + o2_1);

  // q
#pragma unroll
  for (int dt = 0; dt < 16; dt++) {
    float bias = bqc[dt * 16 + c];
    f32x4 acc = {bias, bias, bias, bias};
    acc = MFMA16(af0, *(const short8*)(wqc + (dt * 16 + c) * 64 + g * 8), acc);
    acc = MFMA16(af1, *(const short8*)(wqc + (dt * 16 + c) * 64 + 32 + g * 8), acc);
#pragma unroll
    for (int r = 0; r < 4; r++) {
      int row = 4 * g + r;
      *(unsigned short*)(tlb + row * 512 + ((dt * 32 + 2 * c) ^ ((row & 7) << 4))) = f2bf(acc[r]);
    }
  }
  __syncthreads();
#pragma unroll
  for (int c2 = 0; c2 < 8; c2++) {
    int flat = c2 * 1024 + l * 16;
    int rowt = flat >> 9;
    int off = flat & 511;
    short8 d = *(const short8*)(tlb + rowt * 512 + (off ^ ((rowt & 7) << 4)));
    *(short8*)((char*)qout + (row0 + rowt) * 512 + off) = d;
  }
  __syncthreads();

  // k
#pragma unroll
  for (int dt = 0; dt < 16; dt++) {
    float bias = bkc[dt * 16 + c];
    f32x4 acc = {bias, bias, bias, bias};
    acc = MFMA16(af0, *(const short8*)(wkc + (dt * 16 + c) * 64 + g * 8), acc);
    acc = MFMA16(af1, *(const short8*)(wkc + (dt * 16 + c) * 64 + 32 + g * 8), acc);
#pragma unroll
    for (int r = 0; r < 4; r++) {
      int row = 4 * g + r;
      *(unsigned short*)(tlb + row * 512 + ((dt * 32 + 2 * c) ^ ((row & 7) << 4))) = f2bf(acc[r]);
    }
  }
  __syncthreads();
#pragma unroll
  for (int c2 = 0; c2 < 8; c2++) {
    int flat = c2 * 1024 + l * 16;
    int rowt = flat >> 9;
    int off = flat & 511;
    short8 d = *(const short8*)(tlb + rowt * 512 + (off ^ ((rowt & 7) << 4)));
    *(short8*)((char*)kout + (row0 + rowt) * 512 + off) = d;
  }

  // v transposed
#pragma unroll
  for (int dt = 0; dt < 16; dt++) {
    float bias = wv_b[dt * 16 + c];
    f32x4 acc = {bias, bias, bias, bias};
    acc = MFMA16(af0, *(const short8*)(wvc + (dt * 16 + c) * 64 + g * 8), acc);
    acc = MFMA16(af1, *(const short8*)(wvc + (dt * 16 + c) * 64 + 32 + g * 8), acc);
    ushort4v pk;
#pragma unroll
    for (int r = 0; r < 4; r++) pk[r] = f2bf(acc[r]);
    *(ushort4v*)(vtout + ((size_t)b * 256 + dt * 16 + c) * NN + i0 + 4 * g) = pk;
  }
}

// ---------------------------------------------------------------------------
// Kernel 2 (pass 1): softmax denominators l_h.  512 thr / 8 waves; wave owns
// 32 rows (t2-paired: each K B-frag feeds 2 MFMA) and a 32-j half (sub) of
// the 64-j tile.  128 rows/block, y=4 j-quarters, grid 512 -> 2 blocks/CU,
// 16 waves/CU.  l partials: slice y*2+sub (8 slices).
// ---------------------------------------------------------------------------
__global__ __launch_bounds__(512, 2) void kpass1(
    const unsigned short* __restrict__ qb, const unsigned short* __restrict__ kb,
    const float* __restrict__ wts, float* __restrict__ lout) {
  __shared__ __align__(1024) char ldsk[2 * 32768];
  int tid = threadIdx.x;
  int w = tid >> 6, l = tid & 63, c = l & 15, g = l >> 4;
  int pr = w >> 1, sub = w & 1;
  int p = blockIdx.x;
  int q = (p & 7) * 64 + (p >> 3);  // XCD swizzle (512 % 8 == 0)
  int y = q >> 7, b = (q >> 4) & 7, it = q & 15;
  int i0 = it * 128 + pr * 32;
  const size_t brow = (size_t)b * NN;

  short8 qf[2][8];
#pragma unroll
  for (int t2 = 0; t2 < 2; t2++) {
    const unsigned short* qr = qb + (brow + i0 + t2 * 16 + c) * DD;
#pragma unroll
    for (int s = 0; s < 8; s++) qf[t2][s] = *(const short8*)(qr + s * 32 + g * 8);
  }
  float ls[4][2][4];
#pragma unroll
  for (int h = 0; h < 4; h++)
#pragma unroll
    for (int t2 = 0; t2 < 2; t2++)
#pragma unroll
      for (int r = 0; r < 4; r++) ls[h][t2][r] = 0.f;
  int swz = (c & 7) << 4;
  int o2_0 = (g * 16) ^ swz;
  int o2_1 = (64 + g * 16) ^ swz;

  // prologue: stage 64-j tile 0 (32KB)
  {
    int jb = y * 512;
#pragma unroll
    for (int call = 0; call < 4; call++) {
      int chunk = call * 512 + tid;
      int j = chunk >> 5;
      int q16 = (chunk & 31) << 4;
      const char* src = (const char*)(kb + (brow + jb + j) * DD) + (q16 ^ ((j & 7) << 4));
      gload16(src, ldsk + (chunk & ~63) * 16);
    }
  }
  for (int jt = 0; jt < 8; jt++) {
    int jb = y * 512 + jt * 64;
    const char* kcur = ldsk + (jt & 1) * 32768;
    char* knxt = ldsk + ((jt + 1) & 1) * 32768;
    __syncthreads();
    if (jt < 7) {
      int jb2 = jb + 64;
#pragma unroll
      for (int call = 0; call < 4; call++) {
        int chunk = call * 512 + tid;
        int j = chunk >> 5;
        int q16 = (chunk & 31) << 4;
        const char* src = (const char*)(kb + (brow + jb2 + j) * DD) + (q16 ^ ((j & 7) << 4));
        gload16(src, knxt + (chunk & ~63) * 16);
      }
    }
    float wm[2];
#pragma unroll
    for (int jt2 = 0; jt2 < 2; jt2++) {
      float wv = wts[brow + jb + sub * 32 + jt2 * 16 + c];
      wm[jt2] = (wv == 0.f) ? 0.f : 1.f;
    }
#pragma unroll
    for (int h = 0; h < 4; h++) {
#pragma unroll
      for (int jt2 = 0; jt2 < 2; jt2++) {
        const char* kr = kcur + (sub * 32 + jt2 * 16 + c) * 512;
        short8 b0 = *(const short8*)(kr + h * 128 + o2_0);
        short8 b1 = *(const short8*)(kr + h * 128 + o2_1);
#pragma unroll
        for (int t2 = 0; t2 < 2; t2++) {
          f32x4 s4 = {0.f, 0.f, 0.f, 0.f};
          s4 = MFMA16(qf[t2][2 * h], b0, s4);
          s4 = MFMA16(qf[t2][2 * h + 1], b1, s4);
#pragma unroll
          for (int r = 0; r < 4; r++) ls[h][t2][r] += EXP2(s4[r]) * wm[jt2];
        }
      }
    }
  }
#pragma unroll
  for (int xm = 1; xm <= 8; xm <<= 1)
#pragma unroll
    for (int h = 0; h < 4; h++)
#pragma unroll
      for (int t2 = 0; t2 < 2; t2++)
#pragma unroll
        for (int r = 0; r < 4; r++) ls[h][t2][r] += __shfl_xor(ls[h][t2][r], xm);
  if (c == 0) {
#pragma unroll
    for (int h = 0; h < 4; h++)
#pragma unroll
      for (int t2 = 0; t2 < 2; t2++)
#pragma unroll
        for (int r = 0; r < 4; r++)
          lout[(((size_t)(y * 2 + sub) * BB + b) * 4 + h) * NN + i0 + t2 * 16 + 4 * g + r] =
              ls[h][t2][r];
  }
}

// ---------------------------------------------------------------------------
// Kernel 3 (pass 2): scores with acc init = -log2(l_h) (no per-elem mul);
// a_j = w_j * sum_h exp2(s+nl); num += a@V.  512 thr / 8 waves; 4 row-groups
// of 32 rows (t2-paired); sub splits j (QK, P via LDS) and d (PV).  Mid-iter
// raw s_barrier (lgkmcnt only, staging stays in flight); __syncthreads at
// iter top drains vmcnt.  128 rows/block, y=4, grid 512 -> 2 blocks/CU.
// ---------------------------------------------------------------------------
__global__ __launch_bounds__(512, 2) void kpass2(
    const unsigned short* __restrict__ qb, const unsigned short* __restrict__ kb,
    const unsigned short* __restrict__ vt, const float* __restrict__ wts,
    const float* __restrict__ lin_, unsigned short* __restrict__ num,
    float* __restrict__ tout) {
  __shared__ __align__(1024) char lds[2 * 16384 + 2 * 16384 + 10240];
  int tid = threadIdx.x;
  int w = tid >> 6, l = tid & 63, c = l & 15, g = l >> 4;
  char* ldsk = lds;            // 2 x 16K K buffers
  char* ldsv = lds + 32768;    // 2 x 16K V buffers
  char* ldsp = lds + 65536;    // P tile [128 rows][80B]
  int pr = w >> 1, sub = w & 1;
  int p = blockIdx.x;
  int q = (p & 7) * 64 + (p >> 3);
  int y = q >> 7, b = (q >> 4) & 7, it = q & 15;
  int i0 = it * 128 + pr * 32;
  const size_t brow = (size_t)b * NN;

  float nl[4][2][4];  // -log2(l_h) acc-init
#pragma unroll
  for (int h = 0; h < 4; h++)
#pragma unroll
    for (int t2 = 0; t2 < 2; t2++)
#pragma unroll
      for (int r = 0; r < 4; r++) {
        float lsum = 0.f;
#pragma unroll
        for (int yy = 0; yy < 8; yy++)
          lsum += lin_[(((size_t)yy * BB + b) * 4 + h) * NN + i0 + t2 * 16 + 4 * g + r];
        nl[h][t2][r] = -log2f(lsum);
      }

  short8 qf[2][8];
#pragma unroll
  for (int t2 = 0; t2 < 2; t2++) {
    const unsigned short* qr = qb + (brow + i0 + t2 * 16 + c) * DD;
#pragma unroll
    for (int s = 0; s < 8; s++) qf[t2][s] = *(const short8*)(qr + s * 32 + g * 8);
  }
  f32x4 acc[2][8];
#pragma unroll
  for (int t2 = 0; t2 < 2; t2++)
#pragma unroll
    for (int dt = 0; dt < 8; dt++) acc[t2][dt] = (f32x4){0.f, 0.f, 0.f, 0.f};
  float tacc[2][4] = {{0.f, 0.f, 0.f, 0.f}, {0.f, 0.f, 0.f, 0.f}};
  int swz = (c & 7) << 4;
  int o2_0 = (g * 16) ^ swz;
  int o2_1 = (64 + g * 16) ^ swz;

  // prologue: stage 32-j K+V tile 0
  {
    int jb = y * 512;
#pragma unroll
    for (int call = 0; call < 2; call++) {  // K [32][256] swizzled
      int chunk = call * 512 + tid;
      int j = chunk >> 5;
      int q16 = (chunk & 31) << 4;
      const char* src = (const char*)(kb + (brow + jb + j) * DD) + (q16 ^ ((j & 7) << 4));
      gload16(src, ldsk + (chunk & ~63) * 16);
    }
#pragma unroll
    for (int call = 0; call < 2; call++) {  // V interleaved [d/16][j/8][16][8]
      int i = call * 512 + tid;
      int cc = i & 15, joct = (i >> 4) & 3, dt2 = i >> 6;
      const char* src = (const char*)(vt + ((size_t)b * 256 + dt2 * 16 + cc) * NN + jb + joct * 8);
      gload16(src, ldsv + (i & ~63) * 16);
    }
  }

  for (int jt = 0; jt < 16; jt++) {
    int jb = y * 512 + jt * 32;
    const char* kcur = ldsk + (jt & 1) * 16384;
    const char* vcur = ldsv + (jt & 1) * 16384;
    char* knxt = ldsk + ((jt + 1) & 1) * 16384;
    char* vnxt = ldsv + ((jt + 1) & 1) * 16384;
    __syncthreads();  // vmcnt drain: cur buffers ready; prev P consumed
    if (jt < 15) {
      int jb2 = jb + 32;
#pragma unroll
      for (int call = 0; call < 2; call++) {
        int chunk = call * 512 + tid;
        int j = chunk >> 5;
        int q16 = (chunk & 31) << 4;
        const char* src = (const char*)(kb + (brow + jb2 + j) * DD) + (q16 ^ ((j & 7) << 4));
        gload16(src, knxt + (chunk & ~63) * 16);
      }
#pragma unroll
      for (int call = 0; call < 2; call++) {
        int i = call * 512 + tid;
        int cc = i & 15, joct = (i >> 4) & 3, dt2 = i >> 6;
        const char* src = (const char*)(vt + ((size_t)b * 256 + dt2 * 16 + cc) * NN + jb2 + joct * 8);
        gload16(src, vnxt + (i & ~63) * 16);
      }
    }
    // ---- QK phase: this wave's 16-j half of the 32-j tile ----
    float wj = wts[brow + jb + sub * 16 + c];
    const char* kr = kcur + (sub * 16 + c) * 512;
    float av[2][4] = {{0.f, 0.f, 0.f, 0.f}, {0.f, 0.f, 0.f, 0.f}};
#pragma unroll
    for (int h = 0; h < 4; h++) {
      short8 b0 = *(const short8*)(kr + h * 128 + o2_0);
      short8 b1 = *(const short8*)(kr + h * 128 + o2_1);
#pragma unroll
      for (int t2 = 0; t2 < 2; t2++) {
        f32x4 s4 = {nl[h][t2][0], nl[h][t2][1], nl[h][t2][2], nl[h][t2][3]};
        s4 = MFMA16(qf[t2][2 * h], b0, s4);
        s4 = MFMA16(qf[t2][2 * h + 1], b1, s4);
#pragma unroll
        for (int r = 0; r < 4; r++) av[t2][r] += EXP2(s4[r]);
      }
    }
#pragma unroll
    for (int t2 = 0; t2 < 2; t2++)
#pragma unroll
      for (int r = 0; r < 4; r++) {
        av[t2][r] *= wj;
        tacc[t2][r] += av[t2][r];
        *(unsigned short*)(ldsp + ((size_t)(pr * 32 + t2 * 16 + 4 * g + r)) * 80 +
                           (sub * 16 + c) * 2) = f2bf(av[t2][r]);
      }
    asm volatile("s_waitcnt lgkmcnt(0)" ::: "memory");
    __builtin_amdgcn_s_barrier();  // P ready; NO vmcnt drain
    asm volatile("" ::: "memory");
    __builtin_amdgcn_sched_barrier(0);
    // ---- PV phase: this wave's 128-d half ----
    short8 pf0 = *(const short8*)(ldsp + (pr * 32 + c) * 80 + g * 16);
    short8 pf1 = *(const short8*)(ldsp + (pr * 32 + 16 + c) * 80 + g * 16);
    const char* vb = vcur + sub * 8192 + g * 256 + c * 16;
#pragma unroll
    for (int dt = 0; dt < 8; dt++) {
      short8 vf = *(const short8*)(vb + dt * 1024);
      acc[0][dt] = MFMA16(pf0, vf, acc[0][dt]);
      acc[1][dt] = MFMA16(pf1, vf, acc[1][dt]);
    }
  }
#pragma unroll
  for (int xm = 1; xm <= 8; xm <<= 1)
#pragma unroll
    for (int t2 = 0; t2 < 2; t2++)
#pragma unroll
      for (int r = 0; r < 4; r++) tacc[t2][r] += __shfl_xor(tacc[t2][r], xm);
#pragma unroll
  for (int t2 = 0; t2 < 2; t2++)
#pragma unroll
    for (int dt = 0; dt < 8; dt++)
#pragma unroll
      for (int r = 0; r < 4; r++)
        num[(((size_t)y * BB + b) * NN + i0 + t2 * 16 + 4 * g + r) * DD + sub * 128 +
            dt * 16 + c] = f2bf(acc[t2][dt][r]);
  if (c == 0)
#pragma unroll
    for (int t2 = 0; t2 < 2; t2++)
#pragma unroll
      for (int r = 0; r < 4; r++)
        tout[((size_t)(y * 2 + sub) * BB + b) * NN + i0 + t2 * 16 + 4 * g + r] = tacc[t2][r];
}

// ---------------------------------------------------------------------------
// Kernel 4: epilogue.  num: 4 partial slices; t/l: 8 partial slices.
// ---------------------------------------------------------------------------
__global__ __launch_bounds__(128, 2) void kfinal(
    const unsigned short* __restrict__ num, const float* __restrict__ tws,
    const float* __restrict__ x, const unsigned short* __restrict__ outwb,
    const float* __restrict__ out_b, const float* __restrict__ ln_g,
    const float* __restrict__ ln_b, const unsigned short* __restrict__ ffnwb,
    const float* __restrict__ ffn_b, float* __restrict__ out) {
  __shared__ __align__(1024) char lds[2 * 2304];
  int tid = threadIdx.x, w = tid >> 6, l = tid & 63, c = l & 15, g = l >> 4;
  int blk = blockIdx.x;
  int b = blk >> 6;
  int i0 = (blk & 63) * 32 + w * 16;
  char* hb = lds + w * 2304;

  short8 af[8];
  {
    const unsigned short* p0 = num + (((size_t)0 * BB + b) * NN + i0 + c) * DD;
    const unsigned short* p1 = num + (((size_t)1 * BB + b) * NN + i0 + c) * DD;
    const unsigned short* p2 = num + (((size_t)2 * BB + b) * NN + i0 + c) * DD;
    const unsigned short* p3 = num + (((size_t)3 * BB + b) * NN + i0 + c) * DD;
#pragma unroll
    for (int s = 0; s < 8; s++) {
      short8 a0 = *(const short8*)(p0 + s * 32 + g * 8);
      short8 a1 = *(const short8*)(p1 + s * 32 + g * 8);
      short8 a2 = *(const short8*)(p2 + s * 32 + g * 8);
      short8 a3 = *(const short8*)(p3 + s * 32 + g * 8);
      short8 o;
#pragma unroll
      for (int t2 = 0; t2 < 8; t2++)
        o[t2] = (short)f2bf(bf2f((unsigned short)a0[t2]) + bf2f((unsigned short)a1[t2]) +
                            bf2f((unsigned short)a2[t2]) + bf2f((unsigned short)a3[t2]));
      af[s] = o;
    }
  }
  float trow[4];
#pragma unroll
  for (int r = 0; r < 4; r++) {
    trow[r] = 0.f;
#pragma unroll
    for (int yy = 0; yy < 8; yy++)
      trow[r] += tws[((size_t)yy * BB + b) * NN + i0 + 4 * g + r];
  }
  f32x4 acc[4];
#pragma unroll
  for (int ct = 0; ct < 4; ct++) {
    acc[ct] = (f32x4){0.f, 0.f, 0.f, 0.f};
#pragma unroll
    for (int s = 0; s < 8; s++)
      acc[ct] = MFMA16(af[s], *(const short8*)(outwb + (ct * 16 + c) * DD + s * 32 + g * 8), acc[ct]);
  }
  float gv[4], bvv[4], obv[4], fbv[4];
#pragma unroll
  for (int ct = 0; ct < 4; ct++) {
    gv[ct] = ln_g[ct * 16 + c]; bvv[ct] = ln_b[ct * 16 + c];
    obv[ct] = out_b[ct * 16 + c]; fbv[ct] = ffn_b[ct * 16 + c];
  }
  float o1[4][4];
#pragma unroll
  for (int ct = 0; ct < 4; ct++)
#pragma unroll
    for (int r = 0; r < 4; r++)
      o1[ct][r] = x[((size_t)b * NN + i0 + 4 * g + r) * EE + ct * 16 + c] +
                  acc[ct][r] / trow[r] + obv[ct];
  float h1[4][4];
#pragma unroll
  for (int r = 0; r < 4; r++) {
    float s = o1[0][r] + o1[1][r] + o1[2][r] + o1[3][r];
    float s2 = o1[0][r] * o1[0][r] + o1[1][r] * o1[1][r] +
               o1[2][r] * o1[2][r] + o1[3][r] * o1[3][r];
#pragma unroll
    for (int xm = 1; xm < 16; xm <<= 1) { s += __shfl_xor(s, xm); s2 += __shfl_xor(s2, xm); }
    float mean = s * (1.f / 64.f);
    float var = s2 * (1.f / 64.f) - mean * mean;
    float rstd = rsqrtf(var + 1e-5f);
#pragma unroll
    for (int ct = 0; ct < 4; ct++)
      h1[ct][r] = (o1[ct][r] - mean) * rstd * gv[ct] + bvv[ct];
  }
#pragma unroll
  for (int ct = 0; ct < 4; ct++)
#pragma unroll
    for (int r = 0; r < 4; r++)
      *(unsigned short*)(hb + (4 * g + r) * 144 + ct * 32 + 2 * c) = f2bf(h1[ct][r]);
  asm volatile("s_waitcnt lgkmcnt(0)" ::: "memory");
  __builtin_amdgcn_sched_barrier(0);
  short8 hf0 = *(const short8*)(hb + c * 144 + g * 16);
  short8 hf1 = *(const short8*)(hb + c * 144 + 64 + g * 16);
  f32x4 a2[4];
#pragma unroll
  for (int ct = 0; ct < 4; ct++) {
    a2[ct] = (f32x4){0.f, 0.f, 0.f, 0.f};
    a2[ct] = MFMA16(hf0, *(const short8*)(ffnwb + (ct * 16 + c) * EE + g * 8), a2[ct]);
    a2[ct] = MFMA16(hf1, *(const short8*)(ffnwb + (ct * 16 + c) * EE + 32 + g * 8), a2[ct]);
  }
  float o3[4][4];
#pragma unroll
  for (int ct = 0; ct < 4; ct++)
#pragma unroll
    for (int r = 0; r < 4; r++) {
      float vv = a2[ct][r] + fbv[ct];
      float sp = fmaxf(vv, 0.f) + log1pf(expf(-fabsf(vv)));
      o3[ct][r] = o1[ct][r] + sp;
    }
#pragma unroll
  for (int r = 0; r < 4; r++) {
    float s = o3[0][r] + o3[1][r] + o3[2][r] + o3[3][r];
    float s2 = o3[0][r] * o3[0][r] + o3[1][r] * o3[1][r] +
               o3[2][r] * o3[2][r] + o3[3][r] * o3[3][r];
#pragma unroll
    for (int xm = 1; xm < 16; xm <<= 1) { s += __shfl_xor(s, xm); s2 += __shfl_xor(s2, xm); }
    float mean = s * (1.f / 64.f);
    float var = s2 * (1.f / 64.f) - mean * mean;
    float rstd = rsqrtf(var + 1e-5f);
#pragma unroll
    for (int ct = 0; ct < 4; ct++)
      out[((size_t)b * NN + i0 + 4 * g + r) * EE + ct * 16 + c] =
          (o3[ct][r] - mean) * rstd * gv[ct] + bvv[ct];
  }
}

// ---------------------------------------------------------------------------
extern "C" void kernel_launch(void* const* d_in, const int* in_sizes, int n_in,
                              void* d_out, int out_size, void* d_ws, size_t ws_size,
                              hipStream_t stream) {
  (void)in_sizes; (void)n_in; (void)out_size; (void)ws_size;
  const float* x = (const float*)d_in[0];
  const float* wts = (const float*)d_in[1];
  const float* ln_g = (const float*)d_in[2];
  const float* ln_b = (const float*)d_in[3];
  const float* wq_w = (const float*)d_in[4];
  const float* wq_b = (const float*)d_in[5];
  const float* wk_w = (const float*)d_in[6];
  const float* wk_b = (const float*)d_in[7];
  const float* wv_w = (const float*)d_in[8];
  const float* wv_b = (const float*)d_in[9];
  const float* mq_w = (const float*)d_in[10];
  const float* mq_b = (const float*)d_in[11];
  const float* mk_w = (const float*)d_in[12];
  const float* mk_b = (const float*)d_in[13];
  const float* out_w = (const float*)d_in[14];
  const float* out_b = (const float*)d_in[15];
  const float* ffn_w = (const float*)d_in[16];
  const float* ffn_b = (const float*)d_in[17];
  float* out = (float*)d_out;

  char* ws = (char*)d_ws;
  unsigned short* qb = (unsigned short*)(ws + 0);          //  8.4 MB
  unsigned short* kb = (unsigned short*)(ws + 8388608);    //  8.4 MB
  unsigned short* vt = (unsigned short*)(ws + 16777216);   //  8.4 MB
  float* l1 = (float*)(ws + 25165824);                     //  2.0 MB (8 slices)
  unsigned short* num = (unsigned short*)(ws + 27262976);  // 33.6 MB (4 slices)
  float* tws = (float*)(ws + 60817408);                    //  0.5 MB (8 slices)
  unsigned short* wqc = (unsigned short*)(ws + 61341696);
  unsigned short* wkc = (unsigned short*)(ws + 61374464);
  unsigned short* wvc = (unsigned short*)(ws + 61407232);
  float* bqc = (float*)(ws + 61440000);
  float* bkc = (float*)(ws + 61441024);
  unsigned short* outwb = (unsigned short*)(ws + 61442048);
  unsigned short* ffnwb = (unsigned short*)(ws + 61474816);

  kprep<<<256, 128, 0, stream>>>(wq_w, wq_b, wk_w, wk_b, wv_w, mq_w, mq_b,
                                 mk_w, mk_b, out_w, ffn_w, wqc, bqc, wkc, bkc,
                                 wvc, outwb, ffnwb);
  kproj<<<512, 128, 0, stream>>>(x, ln_g, ln_b, wqc, bqc, wkc, bkc, wvc, wv_b,
                                 qb, kb, vt);
  kpass1<<<512, 512, 0, stream>>>(qb, kb, wts, l1);
  kpass2<<<512, 512, 0, stream>>>(qb, kb, vt, wts, l1, num, tws);
  kfinal<<<512, 128, 0, stream>>>(num, tws, x, outwb, out_b, ln_g, ln_b, ffnwb,
                                  ffn_b, out);
}

// Round 10
// 251.581 us; speedup vs baseline: 1.0193x; 1.0193x over previous
//
#include <hip/hip_runtime.h>
#include <hip/hip_bf16.h>

#define BB 8
#define NN 2048
#define EE 64
#define DD 256

typedef __attribute__((ext_vector_type(8))) short short8;
typedef __attribute__((ext_vector_type(4))) float f32x4;
typedef __attribute__((ext_vector_type(4))) unsigned short ushort4v;

#define MFMA16(a, b, c) __builtin_amdgcn_mfma_f32_16x16x32_bf16((a), (b), (c), 0, 0, 0)

#if __has_builtin(__builtin_amdgcn_exp2f)
#define EXP2(x) __builtin_amdgcn_exp2f(x)
#else
#define EXP2(x) exp2f(x)
#endif

__device__ inline void gload16(const void* g, void* l) {
  __builtin_amdgcn_global_load_lds(
      (const __attribute__((address_space(1))) unsigned int*)g,
      (__attribute__((address_space(3))) unsigned int*)l, 16, 0, 0);
}

__device__ inline float bf2f(unsigned short u) {
  union { unsigned int i; float f; } v;
  v.i = ((unsigned int)u) << 16;
  return v.f;
}
__device__ inline unsigned short f2bf(float f) {
  union { float f; unsigned int i; } v;
  v.f = f;
  unsigned int r = v.i + 0x7FFFu + ((v.i >> 16) & 1u);
  return (unsigned short)(r >> 16);
}

// ---------------------------------------------------------------------------
// Kernel P: combine weights, convert to bf16.
// ---------------------------------------------------------------------------
__global__ __launch_bounds__(128) void kprep(
    const float* __restrict__ wq_w, const float* __restrict__ wq_b,
    const float* __restrict__ wk_w, const float* __restrict__ wk_b,
    const float* __restrict__ wv_w, const float* __restrict__ mq_w,
    const float* __restrict__ mq_b, const float* __restrict__ mk_w,
    const float* __restrict__ mk_b, const float* __restrict__ out_w,
    const float* __restrict__ ffn_w,
    unsigned short* __restrict__ wqc, float* __restrict__ bqc,
    unsigned short* __restrict__ wkc, float* __restrict__ bkc,
    unsigned short* __restrict__ wvc, unsigned short* __restrict__ outwb,
    unsigned short* __restrict__ ffnwb) {
  const float SC = 0.18033688011112042f;  // log2(e)/8
  int o = blockIdx.x;
  int t = threadIdx.x;
  if (t < 64) {
    float acc = 0.f;
#pragma unroll 4
    for (int d = 0; d < 256; d++) acc += mq_w[o * 256 + d] * wq_w[d * 64 + t];
    wqc[o * 64 + t] = f2bf(acc * SC);
  } else {
    int k = t - 64;
    float acc = 0.f;
#pragma unroll 4
    for (int d = 0; d < 256; d++) acc += mk_w[o * 256 + d] * wk_w[d * 64 + k];
    wkc[o * 64 + k] = f2bf(acc);
  }
  if (t == 0) {
    float acc = 0.f;
    for (int d = 0; d < 256; d++) acc += mq_w[o * 256 + d] * wq_b[d];
    bqc[o] = (acc + mq_b[o]) * SC;
  }
  if (t == 64) {
    float acc = 0.f;
    for (int d = 0; d < 256; d++) acc += mk_w[o * 256 + d] * wk_b[d];
    bkc[o] = acc + mk_b[o];
  }
  int gid = o * 128 + t;
  if (gid < 16384) {
    wvc[gid] = f2bf(wv_w[gid]);
    outwb[gid] = f2bf(out_w[gid]);
  }
  if (gid < 4096) ffnwb[gid] = f2bf(ffn_w[gid]);
}

// ---------------------------------------------------------------------------
// Kernel 1: LayerNorm + q/k/v projections (v stored transposed).
// ---------------------------------------------------------------------------
__global__ __launch_bounds__(128, 2) void kproj(
    const float* __restrict__ x, const float* __restrict__ ln_g,
    const float* __restrict__ ln_b, const unsigned short* __restrict__ wqc,
    const float* __restrict__ bqc, const unsigned short* __restrict__ wkc,
    const float* __restrict__ bkc, const unsigned short* __restrict__ wvc,
    const float* __restrict__ wv_b, unsigned short* __restrict__ qout,
    unsigned short* __restrict__ kout, unsigned short* __restrict__ vtout) {
  __shared__ __align__(1024) char lds[2 * 10240];
  int tid = threadIdx.x;
  int w = tid >> 6, l = tid & 63;
  int c = l & 15, g = l >> 4;
  int blk = blockIdx.x;
  int b = blk >> 6;
  int i0 = (blk & 63) * 32 + w * 16;
  size_t row0 = (size_t)b * NN + i0;
  char* xnb = lds + w * 10240;
  char* tlb = lds + w * 10240 + 2048;

  int rl = l >> 2;
  int cc = (l & 3) * 16;
  float xv[16];
  {
    const float* xr = x + (row0 + rl) * EE + cc;
#pragma unroll
    for (int i = 0; i < 4; i++) {
      float4 v = *(const float4*)(xr + i * 4);
      xv[i * 4 + 0] = v.x; xv[i * 4 + 1] = v.y;
      xv[i * 4 + 2] = v.z; xv[i * 4 + 3] = v.w;
    }
  }
  float s = 0.f, s2 = 0.f;
#pragma unroll
  for (int i = 0; i < 16; i++) { s += xv[i]; s2 += xv[i] * xv[i]; }
  s += __shfl_xor(s, 1); s += __shfl_xor(s, 2);
  s2 += __shfl_xor(s2, 1); s2 += __shfl_xor(s2, 2);
  float mean = s * (1.f / 64.f);
  float var = s2 * (1.f / 64.f) - mean * mean;
  float rstd = rsqrtf(var + 1e-5f);
  {
    int swzr = (rl & 7) << 4;
    unsigned short pk[16];
#pragma unroll
    for (int i = 0; i < 16; i++)
      pk[i] = f2bf((xv[i] - mean) * rstd * ln_g[cc + i] + ln_b[cc + i]);
#pragma unroll
    for (int hh = 0; hh < 2; hh++) {
      short8 d;
#pragma unroll
      for (int i = 0; i < 8; i++) d[i] = (short)pk[hh * 8 + i];
      *(short8*)(xnb + rl * 128 + (((l & 3) * 32 + hh * 16) ^ swzr)) = d;
    }
  }
  __syncthreads();

  int swz = (c & 7) << 4;
  int o2_0 = (g * 16) ^ swz;
  int o2_1 = (64 + g * 16) ^ swz;
  short8 af0 = *(const short8*)(xnb + c * 128 + o2_0);
  short8 af1 = *(const short8*)(xnb + c * 128 + o2_1);

  // q
#pragma unroll
  for (int dt = 0; dt < 16; dt++) {
    float bias = bqc[dt * 16 + c];
    f32x4 acc = {bias, bias, bias, bias};
    acc = MFMA16(af0, *(const short8*)(wqc + (dt * 16 + c) * 64 + g * 8), acc);
    acc = MFMA16(af1, *(const short8*)(wqc + (dt * 16 + c) * 64 + 32 + g * 8), acc);
#pragma unroll
    for (int r = 0; r < 4; r++) {
      int row = 4 * g + r;
      *(unsigned short*)(tlb + row * 512 + ((dt * 32 + 2 * c) ^ ((row & 7) << 4))) = f2bf(acc[r]);
    }
  }
  __syncthreads();
#pragma unroll
  for (int c2 = 0; c2 < 8; c2++) {
    int flat = c2 * 1024 + l * 16;
    int rowt = flat >> 9;
    int off = flat & 511;
    short8 d = *(const short8*)(tlb + rowt * 512 + (off ^ ((rowt & 7) << 4)));
    *(short8*)((char*)qout + (row0 + rowt) * 512 + off) = d;
  }
  __syncthreads();

  // k
#pragma unroll
  for (int dt = 0; dt < 16; dt++) {
    float bias = bkc[dt * 16 + c];
    f32x4 acc = {bias, bias, bias, bias};
    acc = MFMA16(af0, *(const short8*)(wkc + (dt * 16 + c) * 64 + g * 8), acc);
    acc = MFMA16(af1, *(const short8*)(wkc + (dt * 16 + c) * 64 + 32 + g * 8), acc);
#pragma unroll
    for (int r = 0; r < 4; r++) {
      int row = 4 * g + r;
      *(unsigned short*)(tlb + row * 512 + ((dt * 32 + 2 * c) ^ ((row & 7) << 4))) = f2bf(acc[r]);
    }
  }
  __syncthreads();
#pragma unroll
  for (int c2 = 0; c2 < 8; c2++) {
    int flat = c2 * 1024 + l * 16;
    int rowt = flat >> 9;
    int off = flat & 511;
    short8 d = *(const short8*)(tlb + rowt * 512 + (off ^ ((rowt & 7) << 4)));
    *(short8*)((char*)kout + (row0 + rowt) * 512 + off) = d;
  }

  // v transposed
#pragma unroll
  for (int dt = 0; dt < 16; dt++) {
    float bias = wv_b[dt * 16 + c];
    f32x4 acc = {bias, bias, bias, bias};
    acc = MFMA16(af0, *(const short8*)(wvc + (dt * 16 + c) * 64 + g * 8), acc);
    acc = MFMA16(af1, *(const short8*)(wvc + (dt * 16 + c) * 64 + 32 + g * 8), acc);
    ushort4v pk;
#pragma unroll
    for (int r = 0; r < 4; r++) pk[r] = f2bf(acc[r]);
    *(ushort4v*)(vtout + ((size_t)b * 256 + dt * 16 + c) * NN + i0 + 4 * g) = pk;
  }
}

// ---------------------------------------------------------------------------
// Kernel 2 (pass 1): softmax denominators l_h.  512 thr / 8 waves; wave owns
// 32 rows (t2-paired) and a 32-j half (sub) of the 64-j tile.  l partials:
// slice y*2+sub (8 slices).  Double-buffered, stage-before-compute, one
// barrier/iter.
// ---------------------------------------------------------------------------
__global__ __launch_bounds__(512, 2) void kpass1(
    const unsigned short* __restrict__ qb, const unsigned short* __restrict__ kb,
    const float* __restrict__ wts, float* __restrict__ lout) {
  __shared__ __align__(1024) char ldsk[2 * 32768];
  int tid = threadIdx.x;
  int w = tid >> 6, l = tid & 63, c = l & 15, g = l >> 4;
  int pr = w >> 1, sub = w & 1;
  int p = blockIdx.x;
  int q = (p & 7) * 64 + (p >> 3);  // XCD swizzle (512 % 8 == 0)
  int y = q >> 7, b = (q >> 4) & 7, it = q & 15;
  int i0 = it * 128 + pr * 32;
  const size_t brow = (size_t)b * NN;

  short8 qf[2][8];
#pragma unroll
  for (int t2 = 0; t2 < 2; t2++) {
    const unsigned short* qr = qb + (brow + i0 + t2 * 16 + c) * DD;
#pragma unroll
    for (int s = 0; s < 8; s++) qf[t2][s] = *(const short8*)(qr + s * 32 + g * 8);
  }
  float ls[4][2][4];
#pragma unroll
  for (int h = 0; h < 4; h++)
#pragma unroll
    for (int t2 = 0; t2 < 2; t2++)
#pragma unroll
      for (int r = 0; r < 4; r++) ls[h][t2][r] = 0.f;
  int swz = (c & 7) << 4;
  int o2_0 = (g * 16) ^ swz;
  int o2_1 = (64 + g * 16) ^ swz;

  // prologue: stage 64-j tile 0 (32KB)
  {
    int jb = y * 512;
#pragma unroll
    for (int call = 0; call < 4; call++) {
      int chunk = call * 512 + tid;
      int j = chunk >> 5;
      int q16 = (chunk & 31) << 4;
      const char* src = (const char*)(kb + (brow + jb + j) * DD) + (q16 ^ ((j & 7) << 4));
      gload16(src, ldsk + (chunk & ~63) * 16);
    }
  }
  for (int jt = 0; jt < 8; jt++) {
    int jb = y * 512 + jt * 64;
    const char* kcur = ldsk + (jt & 1) * 32768;
    char* knxt = ldsk + ((jt + 1) & 1) * 32768;
    __syncthreads();
    if (jt < 7) {
      int jb2 = jb + 64;
#pragma unroll
      for (int call = 0; call < 4; call++) {
        int chunk = call * 512 + tid;
        int j = chunk >> 5;
        int q16 = (chunk & 31) << 4;
        const char* src = (const char*)(kb + (brow + jb2 + j) * DD) + (q16 ^ ((j & 7) << 4));
        gload16(src, knxt + (chunk & ~63) * 16);
      }
    }
    float wm[2];
#pragma unroll
    for (int jt2 = 0; jt2 < 2; jt2++) {
      float wv = wts[brow + jb + sub * 32 + jt2 * 16 + c];
      wm[jt2] = (wv == 0.f) ? 0.f : 1.f;
    }
#pragma unroll
    for (int h = 0; h < 4; h++) {
#pragma unroll
      for (int jt2 = 0; jt2 < 2; jt2++) {
        const char* kr = kcur + (sub * 32 + jt2 * 16 + c) * 512;
        short8 b0 = *(const short8*)(kr + h * 128 + o2_0);
        short8 b1 = *(const short8*)(kr + h * 128 + o2_1);
#pragma unroll
        for (int t2 = 0; t2 < 2; t2++) {
          f32x4 s4 = {0.f, 0.f, 0.f, 0.f};
          s4 = MFMA16(qf[t2][2 * h], b0, s4);
          s4 = MFMA16(qf[t2][2 * h + 1], b1, s4);
#pragma unroll
          for (int r = 0; r < 4; r++) ls[h][t2][r] += EXP2(s4[r]) * wm[jt2];
        }
      }
    }
  }
#pragma unroll
  for (int xm = 1; xm <= 8; xm <<= 1)
#pragma unroll
    for (int h = 0; h < 4; h++)
#pragma unroll
      for (int t2 = 0; t2 < 2; t2++)
#pragma unroll
        for (int r = 0; r < 4; r++) ls[h][t2][r] += __shfl_xor(ls[h][t2][r], xm);
  if (c == 0) {
#pragma unroll
    for (int h = 0; h < 4; h++)
#pragma unroll
      for (int t2 = 0; t2 < 2; t2++)
#pragma unroll
        for (int r = 0; r < 4; r++)
          lout[(((size_t)(y * 2 + sub) * BB + b) * 4 + h) * NN + i0 + t2 * 16 + 4 * g + r] =
              ls[h][t2][r];
  }
}

// ---------------------------------------------------------------------------
// Kernel 3 (pass 2): R6 structure (best measured).  acc init = -log2(l_h);
// a_j = w_j * sum_h exp2(s+nl); num += a@V.  8 waves x 16 rows; y=4; 32-j
// dbuf K+V tiles; one __syncthreads/iter; P via per-wave LDS tile.
// ---------------------------------------------------------------------------
__global__ __launch_bounds__(512, 2) void kpass2(
    const unsigned short* __restrict__ qb, const unsigned short* __restrict__ kb,
    const unsigned short* __restrict__ vt, const float* __restrict__ wts,
    const float* __restrict__ lin_, unsigned short* __restrict__ num,
    float* __restrict__ tout) {
  __shared__ __align__(1024) char lds[2 * 16384 + 2 * 16384 + 8 * 1280];
  int tid = threadIdx.x;
  int w = tid >> 6, l = tid & 63, c = l & 15, g = l >> 4;
  char* ldsk = lds;            // 2 x 16K K buffers
  char* ldsv = lds + 32768;    // 2 x 16K V buffers
  char* ldsp = lds + 65536 + w * 1280;  // per-wave P tile [16][40] bf16
  int p = blockIdx.x;
  int q = (p & 7) * 64 + (p >> 3);
  int y = q >> 7, b = (q >> 4) & 7, it = q & 15;
  int i0 = it * 128 + w * 16;
  const size_t brow = (size_t)b * NN;

  float nl[16];  // -log2(l_h) acc-init; l summed over 8 slices
#pragma unroll
  for (int h = 0; h < 4; h++)
#pragma unroll
    for (int r = 0; r < 4; r++) {
      float lsum = 0.f;
#pragma unroll
      for (int yy = 0; yy < 8; yy++)
        lsum += lin_[(((size_t)yy * BB + b) * 4 + h) * NN + i0 + 4 * g + r];
      nl[h * 4 + r] = -log2f(lsum);
    }

  short8 qf[8];
  {
    const unsigned short* qr = qb + (brow + i0 + c) * DD;
#pragma unroll
    for (int s = 0; s < 8; s++) qf[s] = *(const short8*)(qr + s * 32 + g * 8);
  }
  f32x4 acc[16];
#pragma unroll
  for (int i = 0; i < 16; i++) acc[i] = (f32x4){0.f, 0.f, 0.f, 0.f};
  float tacc[4] = {0.f, 0.f, 0.f, 0.f};
  int swz = (c & 7) << 4;
  int o2_0 = (g * 16) ^ swz;
  int o2_1 = (64 + g * 16) ^ swz;
  int pw[8];
#pragma unroll
  for (int js = 0; js < 2; js++)
#pragma unroll
    for (int r = 0; r < 4; r++) pw[js * 4 + r] = (4 * g + r) * 80 + js * 32 + 2 * c;
  const char* prd = ldsp + c * 80 + g * 16;

  // prologue: stage 32-j K+V tile 0
  {
    int jb = y * 512;
#pragma unroll
    for (int call = 0; call < 2; call++) {  // K tile [32][256], swizzled
      int chunk = call * 512 + tid;
      int j = chunk >> 5;
      int q16 = (chunk & 31) << 4;
      const char* src = (const char*)(kb + (brow + jb + j) * DD) + (q16 ^ ((j & 7) << 4));
      gload16(src, ldsk + (chunk & ~63) * 16);
    }
#pragma unroll
    for (int call = 0; call < 2; call++) {  // V tile interleaved [d/16][j/8][16][8]
      int i = call * 512 + tid;
      int cc = i & 15, joct = (i >> 4) & 3, dt2 = i >> 6;
      const char* src = (const char*)(vt + ((size_t)b * 256 + dt2 * 16 + cc) * NN + jb + joct * 8);
      gload16(src, ldsv + (i & ~63) * 16);
    }
  }

  for (int jt = 0; jt < 16; jt++) {
    int jb = y * 512 + jt * 32;
    const char* kcur = ldsk + (jt & 1) * 16384;
    const char* vcur = ldsv + (jt & 1) * 16384;
    char* knxt = ldsk + ((jt + 1) & 1) * 16384;
    char* vnxt = ldsv + ((jt + 1) & 1) * 16384;
    __syncthreads();  // drains vmcnt -> cur buffers ready
    if (jt < 15) {
      int jb2 = jb + 32;
#pragma unroll
      for (int call = 0; call < 2; call++) {
        int chunk = call * 512 + tid;
        int j = chunk >> 5;
        int q16 = (chunk & 31) << 4;
        const char* src = (const char*)(kb + (brow + jb2 + j) * DD) + (q16 ^ ((j & 7) << 4));
        gload16(src, knxt + (chunk & ~63) * 16);
      }
#pragma unroll
      for (int call = 0; call < 2; call++) {
        int i = call * 512 + tid;
        int cc = i & 15, joct = (i >> 4) & 3, dt2 = i >> 6;
        const char* src = (const char*)(vt + ((size_t)b * 256 + dt2 * 16 + cc) * NN + jb2 + joct * 8);
        gload16(src, vnxt + (i & ~63) * 16);
      }
    }
    float wj[2];
#pragma unroll
    for (int js = 0; js < 2; js++) wj[js] = wts[brow + jb + js * 16 + c];
    const char* kb0 = kcur + c * 512;
    const char* vb0 = vcur + c * 16;
    float av[2][4];
#pragma unroll
    for (int js = 0; js < 2; js++) {
#pragma unroll
      for (int r = 0; r < 4; r++) av[js][r] = 0.f;
#pragma unroll
      for (int h = 0; h < 4; h++) {
        f32x4 s4 = {nl[h * 4 + 0], nl[h * 4 + 1], nl[h * 4 + 2], nl[h * 4 + 3]};
        s4 = MFMA16(qf[2 * h], *(const short8*)(kb0 + js * 8192 + h * 128 + o2_0), s4);
        s4 = MFMA16(qf[2 * h + 1], *(const short8*)(kb0 + js * 8192 + h * 128 + o2_1), s4);
#pragma unroll
        for (int r = 0; r < 4; r++) av[js][r] += EXP2(s4[r]);
      }
#pragma unroll
      for (int r = 0; r < 4; r++) { av[js][r] *= wj[js]; tacc[r] += av[js][r]; }
    }
#pragma unroll
    for (int js = 0; js < 2; js++)
#pragma unroll
      for (int r = 0; r < 4; r++)
        *(unsigned short*)(ldsp + pw[js * 4 + r]) = f2bf(av[js][r]);
    asm volatile("s_waitcnt lgkmcnt(0)" ::: "memory");
    __builtin_amdgcn_sched_barrier(0);
    short8 pf = *(const short8*)prd;
#pragma unroll
    for (int dt = 0; dt < 16; dt++) {
      short8 vf = *(const short8*)(vb0 + dt * 1024 + g * 256);
      acc[dt] = MFMA16(pf, vf, acc[dt]);
    }
  }
#pragma unroll
  for (int xm = 1; xm <= 8; xm <<= 1)
#pragma unroll
    for (int r = 0; r < 4; r++) tacc[r] += __shfl_xor(tacc[r], xm);
#pragma unroll
  for (int dt = 0; dt < 16; dt++)
#pragma unroll
    for (int r = 0; r < 4; r++)
      num[(((size_t)y * BB + b) * NN + i0 + 4 * g + r) * DD + dt * 16 + c] = f2bf(acc[dt][r]);
  if (c == 0)
#pragma unroll
    for (int r = 0; r < 4; r++)
      tout[((size_t)y * BB + b) * NN + i0 + 4 * g + r] = tacc[r];
}

// ---------------------------------------------------------------------------
// Kernel 4: epilogue.  num slices summed via fully-COALESCED b128 loads
// (phase A) into a swizzled LDS tile; A-frags read from LDS (phase B).
// num: 4 slices; t: 4 slices (kpass2 y).
// ---------------------------------------------------------------------------
__global__ __launch_bounds__(128, 2) void kfinal(
    const unsigned short* __restrict__ num, const float* __restrict__ tws,
    const float* __restrict__ x, const unsigned short* __restrict__ outwb,
    const float* __restrict__ out_b, const float* __restrict__ ln_g,
    const float* __restrict__ ln_b, const unsigned short* __restrict__ ffnwb,
    const float* __restrict__ ffn_b, float* __restrict__ out) {
  __shared__ __align__(1024) char lds[16384 + 2 * 2304];
  int tid = threadIdx.x, w = tid >> 6, l = tid & 63, c = l & 15, g = l >> 4;
  int blk = blockIdx.x;
  int b = blk >> 6;
  int i0t = (blk & 63) * 32;   // 32-row tile base
  int i0 = i0t + w * 16;       // this wave's 16 rows
  char* nb = lds;              // [32 rows][512B], row&15 XOR-swizzled
  char* hb = lds + 16384 + w * 2304;

  // ---- Phase A: coalesced sum of 4 num slices into LDS ----
  {
    const size_t slice = (size_t)BB * NN * DD;
    const unsigned short* nbase = num + ((size_t)b * NN + i0t) * DD;
#pragma unroll
    for (int sw = 0; sw < 8; sw++) {
      int flat = sw * 1024 + tid * 8;  // bf16 element index within [32][256]
      short8 a0 = *(const short8*)(nbase + 0 * slice + flat);
      short8 a1 = *(const short8*)(nbase + 1 * slice + flat);
      short8 a2 = *(const short8*)(nbase + 2 * slice + flat);
      short8 a3 = *(const short8*)(nbase + 3 * slice + flat);
      short8 o;
#pragma unroll
      for (int t2 = 0; t2 < 8; t2++)
        o[t2] = (short)f2bf(bf2f((unsigned short)a0[t2]) + bf2f((unsigned short)a1[t2]) +
                            bf2f((unsigned short)a2[t2]) + bf2f((unsigned short)a3[t2]));
      int row = flat >> 8;
      int off = (flat & 255) * 2;
      *(short8*)(nb + row * 512 + (off ^ ((row & 15) << 4))) = o;
    }
  }
  __syncthreads();

  // ---- Phase B: A-frags from LDS ----
  short8 af[8];
  {
    int row = w * 16 + c;
    int swzr = (row & 15) << 4;
#pragma unroll
    for (int s = 0; s < 8; s++)
      af[s] = *(const short8*)(nb + row * 512 + ((s * 64 + g * 16) ^ swzr));
  }
  float trow[4];
#pragma unroll
  for (int r = 0; r < 4; r++) {
    trow[r] = 0.f;
#pragma unroll
    for (int yy = 0; yy < 4; yy++)
      trow[r] += tws[((size_t)yy * BB + b) * NN + i0 + 4 * g + r];
  }
  f32x4 acc[4];
#pragma unroll
  for (int ct = 0; ct < 4; ct++) {
    acc[ct] = (f32x4){0.f, 0.f, 0.f, 0.f};
#pragma unroll
    for (int s = 0; s < 8; s++)
      acc[ct] = MFMA16(af[s], *(const short8*)(outwb + (ct * 16 + c) * DD + s * 32 + g * 8), acc[ct]);
  }
  float gv[4], bvv[4], obv[4], fbv[4];
#pragma unroll
  for (int ct = 0; ct < 4; ct++) {
    gv[ct] = ln_g[ct * 16 + c]; bvv[ct] = ln_b[ct * 16 + c];
    obv[ct] = out_b[ct * 16 + c]; fbv[ct] = ffn_b[ct * 16 + c];
  }
  float o1[4][4];
#pragma unroll
  for (int ct = 0; ct < 4; ct++)
#pragma unroll
    for (int r = 0; r < 4; r++)
      o1[ct][r] = x[((size_t)b * NN + i0 + 4 * g + r) * EE + ct * 16 + c] +
                  acc[ct][r] / trow[r] + obv[ct];
  float h1[4][4];
#pragma unroll
  for (int r = 0; r < 4; r++) {
    float s = o1[0][r] + o1[1][r] + o1[2][r] + o1[3][r];
    float s2 = o1[0][r] * o1[0][r] + o1[1][r] * o1[1][r] +
               o1[2][r] * o1[2][r] + o1[3][r] * o1[3][r];
#pragma unroll
    for (int xm = 1; xm < 16; xm <<= 1) { s += __shfl_xor(s, xm); s2 += __shfl_xor(s2, xm); }
    float mean = s * (1.f / 64.f);
    float var = s2 * (1.f / 64.f) - mean * mean;
    float rstd = rsqrtf(var + 1e-5f);
#pragma unroll
    for (int ct = 0; ct < 4; ct++)
      h1[ct][r] = (o1[ct][r] - mean) * rstd * gv[ct] + bvv[ct];
  }
#pragma unroll
  for (int ct = 0; ct < 4; ct++)
#pragma unroll
    for (int r = 0; r < 4; r++)
      *(unsigned short*)(hb + (4 * g + r) * 144 + ct * 32 + 2 * c) = f2bf(h1[ct][r]);
  asm volatile("s_waitcnt lgkmcnt(0)" ::: "memory");
  __builtin_amdgcn_sched_barrier(0);
  short8 hf0 = *(const short8*)(hb + c * 144 + g * 16);
  short8 hf1 = *(const short8*)(hb + c * 144 + 64 + g * 16);
  f32x4 a2[4];
#pragma unroll
  for (int ct = 0; ct < 4; ct++) {
    a2[ct] = (f32x4){0.f, 0.f, 0.f, 0.f};
    a2[ct] = MFMA16(hf0, *(const short8*)(ffnwb + (ct * 16 + c) * EE + g * 8), a2[ct]);
    a2[ct] = MFMA16(hf1, *(const short8*)(ffnwb + (ct * 16 + c) * EE + 32 + g * 8), a2[ct]);
  }
  float o3[4][4];
#pragma unroll
  for (int ct = 0; ct < 4; ct++)
#pragma unroll
    for (int r = 0; r < 4; r++) {
      float vv = a2[ct][r] + fbv[ct];
      float sp = fmaxf(vv, 0.f) + log1pf(expf(-fabsf(vv)));
      o3[ct][r] = o1[ct][r] + sp;
    }
#pragma unroll
  for (int r = 0; r < 4; r++) {
    float s = o3[0][r] + o3[1][r] + o3[2][r] + o3[3][r];
    float s2 = o3[0][r] * o3[0][r] + o3[1][r] * o3[1][r] +
               o3[2][r] * o3[2][r] + o3[3][r] * o3[3][r];
#pragma unroll
    for (int xm = 1; xm < 16; xm <<= 1) { s += __shfl_xor(s, xm); s2 += __shfl_xor(s2, xm); }
    float mean = s * (1.f / 64.f);
    float var = s2 * (1.f / 64.f) - mean * mean;
    float rstd = rsqrtf(var + 1e-5f);
#pragma unroll
    for (int ct = 0; ct < 4; ct++)
      out[((size_t)b * NN + i0 + 4 * g + r) * EE + ct * 16 + c] =
          (o3[ct][r] - mean) * rstd * gv[ct] + bvv[ct];
  }
}

// ---------------------------------------------------------------------------
extern "C" void kernel_launch(void* const* d_in, const int* in_sizes, int n_in,
                              void* d_out, int out_size, void* d_ws, size_t ws_size,
                              hipStream_t stream) {
  (void)in_sizes; (void)n_in; (void)out_size; (void)ws_size;
  const float* x = (const float*)d_in[0];
  const float* wts = (const float*)d_in[1];
  const float* ln_g = (const float*)d_in[2];
  const float* ln_b = (const float*)d_in[3];
  const float* wq_w = (const float*)d_in[4];
  const float* wq_b = (const float*)d_in[5];
  const float* wk_w = (const float*)d_in[6];
  const float* wk_b = (const float*)d_in[7];
  const float* wv_w = (const float*)d_in[8];
  const float* wv_b = (const float*)d_in[9];
  const float* mq_w = (const float*)d_in[10];
  const float* mq_b = (const float*)d_in[11];
  const float* mk_w = (const float*)d_in[12];
  const float* mk_b = (const float*)d_in[13];
  const float* out_w = (const float*)d_in[14];
  const float* out_b = (const float*)d_in[15];
  const float* ffn_w = (const float*)d_in[16];
  const float* ffn_b = (const float*)d_in[17];
  float* out = (float*)d_out;

  char* ws = (char*)d_ws;
  unsigned short* qb = (unsigned short*)(ws + 0);          //  8.4 MB
  unsigned short* kb = (unsigned short*)(ws + 8388608);    //  8.4 MB
  unsigned short* vt = (unsigned short*)(ws + 16777216);   //  8.4 MB
  float* l1 = (float*)(ws + 25165824);                     //  2.0 MB (8 slices)
  unsigned short* num = (unsigned short*)(ws + 27262976);  // 33.6 MB (4 slices)
  float* tws = (float*)(ws + 60817408);                    //  0.5 MB (4 used)
  unsigned short* wqc = (unsigned short*)(ws + 61341696);
  unsigned short* wkc = (unsigned short*)(ws + 61374464);
  unsigned short* wvc = (unsigned short*)(ws + 61407232);
  float* bqc = (float*)(ws + 61440000);
  float* bkc = (float*)(ws + 61441024);
  unsigned short* outwb = (unsigned short*)(ws + 61442048);
  unsigned short* ffnwb = (unsigned short*)(ws + 61474816);

  kprep<<<256, 128, 0, stream>>>(wq_w, wq_b, wk_w, wk_b, wv_w, mq_w, mq_b,
                                 mk_w, mk_b, out_w, ffn_w, wqc, bqc, wkc, bkc,
                                 wvc, outwb, ffnwb);
  kproj<<<512, 128, 0, stream>>>(x, ln_g, ln_b, wqc, bqc, wkc, bkc, wvc, wv_b,
                                 qb, kb, vt);
  kpass1<<<512, 512, 0, stream>>>(qb, kb, wts, l1);
  kpass2<<<512, 512, 0, stream>>>(qb, kb, vt, wts, l1, num, tws);
  kfinal<<<512, 128, 0, stream>>>(num, tws, x, outwb, out_b, ln_g, ln_b, ffnwb,
                                  ffn_b, out);
}